// Round 12
// baseline (191.173 us; speedup 1.0000x reference)
//
#include <hip/hip_runtime.h>

// ChemResBlock: S=16, A=512, F=64, L=12, 3 layers x 2 convs (shared weights/layer).
// Re-associated: y[o,k,l] = sum_f x[k,f] w[o,l,f];  out[a,o] = sum_j conn[a][j]*yT[o][j],
// j = k*12+l K-MAJOR both sides. conn & yT in FP8 e4m3 (yT scaled 2^14).
// R12 = R9 base (best proven) + ONE change: stageB k-split 4->8 (grid 1024,
// 12 steps, 4 blocks/CU) for 2x latency-hiding occupancy. pOut = 8 slices.

typedef __attribute__((ext_vector_type(8))) short bf16x8;
typedef __attribute__((ext_vector_type(4))) float f32x4;
typedef unsigned short u16;
typedef unsigned int u32;
typedef unsigned char u8;
typedef long i64t;

#define YSCALE 16384.0f
#define YINV   (1.0f / 16384.0f)

__device__ __forceinline__ u16 f2bf(float f) {
  union { float f; u32 u; } x; x.f = f;
  u32 r = x.u + 0x7fffu + ((x.u >> 16) & 1u);   // RNE
  return (u16)(r >> 16);
}

__device__ __forceinline__ u32 fp8pk4(float a, float b, float c, float d) {
  u32 w = __builtin_amdgcn_cvt_pk_fp8_f32(a, b, 0u, false);
  return __builtin_amdgcn_cvt_pk_fp8_f32(c, d, w, true);
}
__device__ __forceinline__ u32 fp8one(float v) {
  return __builtin_amdgcn_cvt_pk_fp8_f32(v, v, 0u, false) & 0xffu;
}

__device__ __forceinline__ void gload16(const void* g, void* l) {
  __builtin_amdgcn_global_load_lds((const __attribute__((address_space(1))) u32*)g,
                                   (__attribute__((address_space(3))) u32*)l, 16, 0, 0);
}

// ---------- k_prep: [0,2048) conn->fp8 | [2048,2624) w_pack | [2624,3136) bondw ----------
__global__ __launch_bounds__(256) void k_prep(const float* __restrict__ conn,
                                              const float* __restrict__ filters,
                                              const float* __restrict__ bond,
                                              u8* __restrict__ connQ,
                                              u16* __restrict__ wA,
                                              float* __restrict__ bW) {
  const int bid = blockIdx.x, tid = threadIdx.x;
  if (bid < 2048) {
    // conn f32 -> e4m3, 8 elems/thread/iter. n8 = 50331648/8 = 6291456
    const unsigned n8 = 6291456u, stride = 2048 * 256;
    for (unsigned j = bid * 256 + tid; j < n8; j += stride) {
      const float4* s4 = (const float4*)conn;
      float4 a = s4[2 * (size_t)j], b = s4[2 * (size_t)j + 1];
      uint2 w;
      w.x = fp8pk4(a.x, a.y, a.z, a.w);
      w.y = fp8pk4(b.x, b.y, b.z, b.w);
      ((uint2*)connQ)[j] = w;
    }
  } else if (bid < 2624) {
    // filters (3,64,12,66) -> wA [i][(l*64+o)][f] bf16 (drop bond cols)
    int t = (bid - 2048) * 256 + tid;        // < 147456
    int i = t / 49152;
    int rem = t - i * 49152;
    int row = rem >> 6, f = rem & 63;
    int l = row >> 6, o = row & 63;
    wA[t] = f2bf(filters[((size_t)((i * 64 + o) * 12 + l)) * 66 + f]);
  } else {
    // bondW[i][(sa)*64+o] = sum_{l,j} bond[sa,l,j] * filters[i,o,l,64+j]
    __shared__ float wb[4608];               // [i][o][l*2+j]
    __shared__ float lb[16 * 24];
    const int sa0 = (bid - 2624) * 16;
    for (int idx = tid; idx < 4608; idx += 256) {
      int i = idx / 1536, rem = idx - i * 1536;
      int o = rem / 24, lj = rem - o * 24;
      wb[idx] = filters[((size_t)((i * 64 + o) * 12 + (lj >> 1))) * 66 + 64 + (lj & 1)];
    }
    for (int t = tid; t < 384; t += 256)
      lb[t] = bond[(size_t)sa0 * 24 + t];
    __syncthreads();
#pragma unroll
    for (int it = 0; it < 12; ++it) {
      int idx = it * 256 + tid;              // < 3072 = 16sa x 3i x 64o
      int sl = idx / 192, rem = idx - sl * 192;
      int i = rem >> 6, o = rem & 63;
      float acc = 0.f;
#pragma unroll
      for (int lj = 0; lj < 24; ++lj)
        acc += lb[sl * 24 + lj] * wb[i * 1536 + o * 24 + lj];
      bW[(size_t)i * 524288 + (size_t)(sa0 + sl) * 64 + o] = acc;
    }
  }
}

// ---------- k_yT: x (node | 8-slice reduce+epilogue) -> yT fp8 [s][o][k*12+l], xYSCALE ----
// grid (16 ktile, 16 s), 256 thr. bf16 MFMA internally; K-MAJOR fp8 writes.
__global__ __launch_bounds__(256) void k_yT(const float* __restrict__ node,
                                            const float* __restrict__ pOut,
                                            const float* __restrict__ bias,
                                            const u16* __restrict__ wAf,
                                            u8* __restrict__ yT,
                                            int mode, int addNode) {
  const int s = blockIdx.y, k0 = blockIdx.x * 32;
  __shared__ u16 xld[32 * 64];               // bf16 x tile, 16B-slot XOR (row&7)
  __shared__ u16 Z[12 * 64 * 36];            // [l][o][k pad 36]; low byte = fp8
  const int tid = threadIdx.x, lane = tid & 63, wid = tid >> 6;
  const int r = lane & 15, g = lane >> 4;

  {
    const int row = tid >> 3, f0 = (tid & 7) * 8;
    const size_t e = ((size_t)(s * 512) + k0 + row) * 64 + f0;
    float v[8];
    if (mode == 0) {
      float4 a = *(const float4*)&node[e], b = *(const float4*)&node[e + 4];
      v[0] = a.x; v[1] = a.y; v[2] = a.z; v[3] = a.w;
      v[4] = b.x; v[5] = b.y; v[6] = b.z; v[7] = b.w;
    } else {
      float4 sa = {0, 0, 0, 0}, sb = {0, 0, 0, 0};
#pragma unroll
      for (int q = 0; q < 8; ++q) {
        float4 a = *(const float4*)&pOut[(size_t)q * 524288 + e];
        float4 b = *(const float4*)&pOut[(size_t)q * 524288 + e + 4];
        sa.x += a.x; sa.y += a.y; sa.z += a.z; sa.w += a.w;
        sb.x += b.x; sb.y += b.y; sb.z += b.z; sb.w += b.w;
      }
      float4 ba = *(const float4*)&bias[e], bb = *(const float4*)&bias[e + 4];
      sa.x = sa.x * YINV + ba.x; sa.y = sa.y * YINV + ba.y;
      sa.z = sa.z * YINV + ba.z; sa.w = sa.w * YINV + ba.w;
      sb.x = sb.x * YINV + bb.x; sb.y = sb.y * YINV + bb.y;
      sb.z = sb.z * YINV + bb.z; sb.w = sb.w * YINV + bb.w;
      if (addNode) {
        float4 na = *(const float4*)&node[e], nb = *(const float4*)&node[e + 4];
        sa.x += na.x; sa.y += na.y; sa.z += na.z; sa.w += na.w;
        sb.x += nb.x; sb.y += nb.y; sb.z += nb.z; sb.w += nb.w;
      }
      v[0] = fmaxf(sa.x, 0.f); v[1] = fmaxf(sa.y, 0.f);
      v[2] = fmaxf(sa.z, 0.f); v[3] = fmaxf(sa.w, 0.f);
      v[4] = fmaxf(sb.x, 0.f); v[5] = fmaxf(sb.y, 0.f);
      v[6] = fmaxf(sb.z, 0.f); v[7] = fmaxf(sb.w, 0.f);
    }
    ushort4 h0, h1;
    h0.x = f2bf(v[0]); h0.y = f2bf(v[1]); h0.z = f2bf(v[2]); h0.w = f2bf(v[3]);
    h1.x = f2bf(v[4]); h1.y = f2bf(v[5]); h1.z = f2bf(v[6]); h1.w = f2bf(v[7]);
    const int slot = (f0 >> 3) ^ (row & 7);
    *(ushort4*)&xld[row * 64 + slot * 8] = h0;
    *(ushort4*)&xld[row * 64 + slot * 8 + 4] = h1;
  }
  __syncthreads();

#pragma unroll
  for (int lw = 0; lw < 3; ++lw) {
    const int l = wid * 3 + lw;
    f32x4 acc[4][2] = {};                    // [ot][kt]
#pragma unroll
    for (int ks = 0; ks < 2; ++ks) {
      bf16x8 bv[2];
#pragma unroll
      for (int kt = 0; kt < 2; ++kt) {
        const int kk = kt * 16 + r;
        bv[kt] = *(const bf16x8*)&xld[kk * 64 + (((ks * 4 + g) ^ (kk & 7)) << 3)];
      }
#pragma unroll
      for (int ot = 0; ot < 4; ++ot) {
        bf16x8 av = *(const bf16x8*)&wAf[(size_t)(l * 64 + ot * 16 + r) * 64 + ks * 32 + g * 8];
#pragma unroll
        for (int kt = 0; kt < 2; ++kt)
          acc[ot][kt] = __builtin_amdgcn_mfma_f32_16x16x32_bf16(av, bv[kt], acc[ot][kt], 0, 0, 0);
      }
    }
#pragma unroll
    for (int ot = 0; ot < 4; ++ot)
#pragma unroll
      for (int kt = 0; kt < 2; ++kt)
#pragma unroll
        for (int r2 = 0; r2 < 4; ++r2) {
          int o = ot * 16 + g * 4 + r2, k = kt * 16 + r;
          Z[l * 2304 + o * 36 + k] = (u16)fp8one(acc[ot][kt][r2] * YSCALE);
        }
  }
  __syncthreads();
  u8* yb = yT + (size_t)s * 393216;
#pragma unroll
  for (int it = 0; it < 8; ++it) {
    int idx = it * 256 + tid;                // 64 o x 32 k
    int o = idx >> 5, k = idx & 31;
    u32 b[12];
#pragma unroll
    for (int l = 0; l < 12; ++l) b[l] = (u32)(Z[l * 2304 + o * 36 + k] & 0xffu);
    u32* dst = (u32*)&yb[(size_t)o * 6144 + (size_t)(k0 + k) * 12];
    dst[0] = b[0] | (b[1] << 8) | (b[2] << 16) | (b[3] << 24);
    dst[1] = b[4] | (b[5] << 8) | (b[6] << 16) | (b[7] << 24);
    dst[2] = b[8] | (b[9] << 8) | (b[10] << 16) | (b[11] << 24);
  }
}

// ---------- stage B (fp8): counted-vmcnt 3-buffer pipeline ----------
// grid 1024 (8 xcd x 2 s x 8 mt x 8 kq), 512 thr, 64x64 tile, BK=64, 12 steps.
// LDS rows 64 B; 16B-slot XOR X(row)=(row^(row>>2))&3, src-side + read-side.
__global__ __launch_bounds__(512, 2) void k_stageB(const u8* __restrict__ connQ,
                                                   const u8* __restrict__ yT,
                                                   float* __restrict__ pOut) {
  const int b = blockIdx.x;
  const int s = (b & 7) * 2 + ((b >> 3) & 1);
  const int mt = (b >> 4) & 7, kq = b >> 7;
  const int row0 = mt * 64, k0 = kq * 768;
  const u8* Ab = connQ + (size_t)(s * 512 + row0) * 6144 + k0;
  const u8* Bb = yT + (size_t)(s * 64) * 6144 + k0;
  __shared__ __align__(16) u8 lds[3 * 2 * 4096];   // 24 KB: [buf][A|B][64*64]
  const int tid = threadIdx.x, lane = tid & 63, wid = tid >> 6;
  const int r = lane & 15, g = lane >> 4;
  const int wr = wid & 3, wc = wid >> 2;
  const int isA = wid < 4;
  const int wseg = (isA ? wid : wid - 4) * 16;     // 16-row staging segment
  const u8* sbase = isA ? Ab : Bb;
  const int lrow = lane >> 2, lslot = lane & 3;    // 16 rows x 4 slots of 16B
  const int side = isA ? 0 : 1;
  f32x4 acc[2] = {};

#define STAGE(T, NB)                                                            \
  {                                                                             \
    const int row = wseg + lrow;                                                \
    const int slot = lslot ^ ((row ^ (row >> 2)) & 3);                          \
    gload16(sbase + (size_t)row * 6144 + (size_t)(T) * 64 + slot * 16,          \
            &lds[((NB) * 2 + side) * 4096 + wseg * 64]);                        \
  }

  STAGE(0, 0);
  STAGE(1, 1);
  int nb = 0;
  for (int t = 0; t < 12; ++t) {
    if (t < 11) { asm volatile("s_waitcnt vmcnt(1)" ::: "memory"); }
    else        { asm volatile("s_waitcnt vmcnt(0)" ::: "memory"); }
    __builtin_amdgcn_s_barrier();
    if (t + 2 < 12) {
      int nb2 = nb + 2; if (nb2 >= 3) nb2 -= 3;
      STAGE(t + 2, nb2);
    }
    {
      const u8* bufA = &lds[(nb * 2 + 0) * 4096];
      const u8* bufB = &lds[(nb * 2 + 1) * 4096];
      const int arow = wr * 16 + r;
      const int ax = (arow ^ (arow >> 2)) & 3;
#pragma unroll
      for (int ks = 0; ks < 2; ++ks) {
        i64t av = *(const i64t*)&bufA[arow * 64 + (((ks * 2 + (g >> 1)) ^ ax) << 4) + ((g & 1) << 3)];
#pragma unroll
        for (int c = 0; c < 2; ++c) {
          const int col = wc * 32 + c * 16 + r;
          const int bx = (col ^ (col >> 2)) & 3;
          i64t bv = *(const i64t*)&bufB[col * 64 + (((ks * 2 + (g >> 1)) ^ bx) << 4) + ((g & 1) << 3)];
          acc[c] = __builtin_amdgcn_mfma_f32_16x16x32_fp8_fp8(av, bv, acc[c], 0, 0, 0);
        }
      }
    }
    if (++nb >= 3) nb -= 3;
  }
#undef STAGE
  float* po = pOut + (size_t)kq * 524288 + ((size_t)(s * 512) + row0) * 64;
#pragma unroll
  for (int c = 0; c < 2; ++c)
#pragma unroll
    for (int r2 = 0; r2 < 4; ++r2) {
      int m = wr * 16 + g * 4 + r2;
      int o = wc * 32 + c * 16 + r;
      po[m * 64 + o] = acc[c][r2];
    }
}

// ---------- final conv epilogue: d_out = relu(sum_q p[q]*YINV + bW + node) f32 ----------
__global__ __launch_bounds__(256) void k_finalLast(const float* __restrict__ pOut,
                                                   const float* __restrict__ bW,
                                                   const float* __restrict__ node,
                                                   float* __restrict__ outF) {
  size_t e = ((size_t)blockIdx.x * 256 + threadIdx.x) * 4;   // < 524288
  float4 sv = {0, 0, 0, 0};
#pragma unroll
  for (int q = 0; q < 8; ++q) {
    float4 a = *(const float4*)&pOut[(size_t)q * 524288 + e];
    sv.x += a.x; sv.y += a.y; sv.z += a.z; sv.w += a.w;
  }
  float4 bw = *(const float4*)&bW[e];
  float4 nd = *(const float4*)&node[e];
  sv.x = fmaxf(sv.x * YINV + bw.x + nd.x, 0.f);
  sv.y = fmaxf(sv.y * YINV + bw.y + nd.y, 0.f);
  sv.z = fmaxf(sv.z * YINV + bw.z + nd.z, 0.f);
  sv.w = fmaxf(sv.w * YINV + bw.w + nd.w, 0.f);
  *(float4*)&outF[e] = sv;
}

// ---------- fallback (f32, correct, slow) if ws too small ----------
__global__ __launch_bounds__(256) void k_fb_conv(const float* __restrict__ x,
                                                 const float* __restrict__ conn,
                                                 const float* __restrict__ bond,
                                                 const float* __restrict__ filt,
                                                 const float* __restrict__ node,
                                                 float* __restrict__ out, int addNode) {
  const int s = blockIdx.y, a = blockIdx.x;
  const int t = threadIdx.x;
  const int f = t & 63, lg = t >> 6;
  __shared__ float ncv[12 * 64];
  __shared__ float red[4][64];
  const float* cb = conn + ((size_t)(s * 512 + a)) * 6144;
  const float* xb = x + (size_t)s * 32768;
  float a0 = 0.f, a1 = 0.f, a2 = 0.f;
  for (int k = 0; k < 512; ++k) {
    float xv = xb[k * 64 + f];
    const float* cr = cb + k * 12 + lg * 3;
    a0 += cr[0] * xv; a1 += cr[1] * xv; a2 += cr[2] * xv;
  }
  ncv[(lg * 3 + 0) * 64 + f] = a0;
  ncv[(lg * 3 + 1) * 64 + f] = a1;
  ncv[(lg * 3 + 2) * 64 + f] = a2;
  __syncthreads();
  float p = 0.f;
  for (int l = lg * 3; l < lg * 3 + 3; ++l) {
    const float* wr = filt + ((size_t)(f * 12 + l)) * 66;
    float q = 0.f;
    for (int f2 = 0; f2 < 64; ++f2) q += ncv[l * 64 + f2] * wr[f2];
    q += bond[((size_t)(s * 512 + a) * 12 + l) * 2 + 0] * wr[64];
    q += bond[((size_t)(s * 512 + a) * 12 + l) * 2 + 1] * wr[65];
    p += q;
  }
  red[lg][f] = p;
  __syncthreads();
  if (t < 64) {
    float v = red[0][t] + red[1][t] + red[2][t] + red[3][t];
    if (addNode) v += node[((size_t)(s * 512 + a)) * 64 + t];
    out[((size_t)(s * 512 + a)) * 64 + t] = fmaxf(v, 0.f);
  }
}

extern "C" void kernel_launch(void* const* d_in, const int* in_sizes, int n_in,
                              void* d_out, int out_size, void* d_ws, size_t ws_size,
                              hipStream_t stream) {
  (void)in_sizes; (void)n_in; (void)out_size;
  const float* node    = (const float*)d_in[0];
  const float* conn    = (const float*)d_in[1];
  const float* bond    = (const float*)d_in[2];
  const float* filters = (const float*)d_in[3];
  float* outF = (float*)d_out;

  const size_t OFF_CONNQ = 0;           // 16*512*6144   = 50,331,648
  const size_t OFF_YT    = 50331648;    // 16*64*6144    =  6,291,456
  const size_t OFF_WA    = 56623104;    // 3*768*64*2    =    294,912
  const size_t OFF_BW    = 56918016;    // 3*16*512*64*4 =  6,291,456
  const size_t OFF_POUT  = 63209472;    // 8*16*512*64*4 = 16,777,216
  const size_t WS_NEED   = 79986688;

  if (ws_size >= WS_NEED) {
    unsigned char* ws = (unsigned char*)d_ws;
    u8*  connQ = (u8*)(ws + OFF_CONNQ);
    u8*  yTb   = (u8*)(ws + OFF_YT);
    u16* wA    = (u16*)(ws + OFF_WA);
    float* bW  = (float*)(ws + OFF_BW);
    float* pO  = (float*)(ws + OFF_POUT);

    k_prep<<<dim3(3136), dim3(256), 0, stream>>>(conn, filters, bond, connQ, wA, bW);
    k_yT<<<dim3(16, 16), dim3(256), 0, stream>>>(node, pO, bW, wA, yTb, 0, 0);
    for (int j = 0; j < 6; ++j) {
      k_stageB<<<dim3(1024), dim3(512), 0, stream>>>(connQ, yTb, pO);
      if (j < 5) {
        k_yT<<<dim3(16, 16), dim3(256), 0, stream>>>(node, pO,
                                                     bW + (size_t)(j >> 1) * 524288,
                                                     wA + (size_t)((j + 1) >> 1) * 49152,
                                                     yTb, 1, j & 1);
      } else {
        k_finalLast<<<dim3(512), dim3(256), 0, stream>>>(pO, bW + (size_t)2 * 524288,
                                                         node, outF);
      }
    }
  } else {
    float* buf = (float*)d_ws;
    const float* xc = node;
    for (int j = 0; j < 6; ++j) {
      int i = j >> 1;
      float* dst = (j & 1) ? outF : buf;
      k_fb_conv<<<dim3(512, 16), dim3(256), 0, stream>>>(xc, conn, bond,
                                                         filters + (size_t)i * 50688,
                                                         node, dst, j & 1);
      xc = dst;
    }
  }
}

// Round 13
// 175.046 us; speedup vs baseline: 1.0921x; 1.0921x over previous
//
#include <hip/hip_runtime.h>

// ChemResBlock: S=16, A=512, F=64, L=12, 3 layers x 2 convs (shared weights/layer).
// Re-associated: y[o,k,l] = sum_f x[k,f] w[o,l,f];  out[a,o] = sum_j conn[a][j]*yT[o][j],
// j = k*12+l K-MAJOR both sides. conn & yT quantized to FP8 e4m3 (yT scaled 2^14).
// R13 = R9 restored byte-for-byte (best measured: 176.3 µs). Ablation record:
//   R10 cast-into-conv0 fusion: neutral. R11 balanced-CVT+3-changes: +9 µs.
//   R12 k-split 8 (2x occupancy): +15 µs -> stageB is BYTES-bound, not latency.

typedef __attribute__((ext_vector_type(8))) short bf16x8;
typedef __attribute__((ext_vector_type(4))) float f32x4;
typedef unsigned short u16;
typedef unsigned int u32;
typedef unsigned char u8;
typedef long i64t;

#define YSCALE 16384.0f
#define YINV   (1.0f / 16384.0f)

__device__ __forceinline__ u16 f2bf(float f) {
  union { float f; u32 u; } x; x.f = f;
  u32 r = x.u + 0x7fffu + ((x.u >> 16) & 1u);   // RNE
  return (u16)(r >> 16);
}

__device__ __forceinline__ u32 fp8pk4(float a, float b, float c, float d) {
  u32 w = __builtin_amdgcn_cvt_pk_fp8_f32(a, b, 0u, false);
  return __builtin_amdgcn_cvt_pk_fp8_f32(c, d, w, true);
}
__device__ __forceinline__ u32 fp8one(float v) {
  return __builtin_amdgcn_cvt_pk_fp8_f32(v, v, 0u, false) & 0xffu;
}

__device__ __forceinline__ void gload16(const void* g, void* l) {
  __builtin_amdgcn_global_load_lds((const __attribute__((address_space(1))) u32*)g,
                                   (__attribute__((address_space(3))) u32*)l, 16, 0, 0);
}

// ---------- k_prep: [0,2048) conn->fp8 | [2048,2624) w_pack | [2624,3136) bondw ----------
__global__ __launch_bounds__(256) void k_prep(const float* __restrict__ conn,
                                              const float* __restrict__ filters,
                                              const float* __restrict__ bond,
                                              u8* __restrict__ connQ,
                                              u16* __restrict__ wA,
                                              float* __restrict__ bW) {
  const int bid = blockIdx.x, tid = threadIdx.x;
  if (bid < 2048) {
    // conn f32 -> e4m3, 8 elems/thread/iter. n8 = 50331648/8 = 6291456
    const unsigned n8 = 6291456u, stride = 2048 * 256;
    for (unsigned j = bid * 256 + tid; j < n8; j += stride) {
      const float4* s4 = (const float4*)conn;
      float4 a = s4[2 * (size_t)j], b = s4[2 * (size_t)j + 1];
      uint2 w;
      w.x = fp8pk4(a.x, a.y, a.z, a.w);
      w.y = fp8pk4(b.x, b.y, b.z, b.w);
      ((uint2*)connQ)[j] = w;
    }
  } else if (bid < 2624) {
    // filters (3,64,12,66) -> wA [i][(l*64+o)][f] bf16 (drop bond cols)
    int t = (bid - 2048) * 256 + tid;        // < 147456
    int i = t / 49152;
    int rem = t - i * 49152;
    int row = rem >> 6, f = rem & 63;
    int l = row >> 6, o = row & 63;
    wA[t] = f2bf(filters[((size_t)((i * 64 + o) * 12 + l)) * 66 + f]);
  } else {
    // bondW[i][(sa)*64+o] = sum_{l,j} bond[sa,l,j] * filters[i,o,l,64+j]
    __shared__ float wb[4608];               // [i][o][l*2+j]
    __shared__ float lb[16 * 24];
    const int sa0 = (bid - 2624) * 16;
    for (int idx = tid; idx < 4608; idx += 256) {
      int i = idx / 1536, rem = idx - i * 1536;
      int o = rem / 24, lj = rem - o * 24;
      wb[idx] = filters[((size_t)((i * 64 + o) * 12 + (lj >> 1))) * 66 + 64 + (lj & 1)];
    }
    for (int t = tid; t < 384; t += 256)
      lb[t] = bond[(size_t)sa0 * 24 + t];
    __syncthreads();
#pragma unroll
    for (int it = 0; it < 12; ++it) {
      int idx = it * 256 + tid;              // < 3072 = 16sa x 3i x 64o
      int sl = idx / 192, rem = idx - sl * 192;
      int i = rem >> 6, o = rem & 63;
      float acc = 0.f;
#pragma unroll
      for (int lj = 0; lj < 24; ++lj)
        acc += lb[sl * 24 + lj] * wb[i * 1536 + o * 24 + lj];
      bW[(size_t)i * 524288 + (size_t)(sa0 + sl) * 64 + o] = acc;
    }
  }
}

// ---------- k_yT: x (node | 4-slice reduce+epilogue) -> yT fp8 [s][o][k*12+l], xYSCALE ----
// grid (16 ktile, 16 s), 256 thr. bf16 MFMA internally; K-MAJOR fp8 writes.
__global__ __launch_bounds__(256) void k_yT(const float* __restrict__ node,
                                            const float* __restrict__ pOut,
                                            const float* __restrict__ bias,
                                            const u16* __restrict__ wAf,
                                            u8* __restrict__ yT,
                                            int mode, int addNode) {
  const int s = blockIdx.y, k0 = blockIdx.x * 32;
  __shared__ u16 xld[32 * 64];               // bf16 x tile, 16B-slot XOR (row&7)
  __shared__ u16 Z[12 * 64 * 36];            // [l][o][k pad 36]; low byte = fp8
  const int tid = threadIdx.x, lane = tid & 63, wid = tid >> 6;
  const int r = lane & 15, g = lane >> 4;

  {
    const int row = tid >> 3, f0 = (tid & 7) * 8;
    const size_t e = ((size_t)(s * 512) + k0 + row) * 64 + f0;
    float v[8];
    if (mode == 0) {
      float4 a = *(const float4*)&node[e], b = *(const float4*)&node[e + 4];
      v[0] = a.x; v[1] = a.y; v[2] = a.z; v[3] = a.w;
      v[4] = b.x; v[5] = b.y; v[6] = b.z; v[7] = b.w;
    } else {
      float4 sa = {0, 0, 0, 0}, sb = {0, 0, 0, 0};
#pragma unroll
      for (int q = 0; q < 4; ++q) {
        float4 a = *(const float4*)&pOut[(size_t)q * 524288 + e];
        float4 b = *(const float4*)&pOut[(size_t)q * 524288 + e + 4];
        sa.x += a.x; sa.y += a.y; sa.z += a.z; sa.w += a.w;
        sb.x += b.x; sb.y += b.y; sb.z += b.z; sb.w += b.w;
      }
      float4 ba = *(const float4*)&bias[e], bb = *(const float4*)&bias[e + 4];
      sa.x = sa.x * YINV + ba.x; sa.y = sa.y * YINV + ba.y;
      sa.z = sa.z * YINV + ba.z; sa.w = sa.w * YINV + ba.w;
      sb.x = sb.x * YINV + bb.x; sb.y = sb.y * YINV + bb.y;
      sb.z = sb.z * YINV + bb.z; sb.w = sb.w * YINV + bb.w;
      if (addNode) {
        float4 na = *(const float4*)&node[e], nb = *(const float4*)&node[e + 4];
        sa.x += na.x; sa.y += na.y; sa.z += na.z; sa.w += na.w;
        sb.x += nb.x; sb.y += nb.y; sb.z += nb.z; sb.w += nb.w;
      }
      v[0] = fmaxf(sa.x, 0.f); v[1] = fmaxf(sa.y, 0.f);
      v[2] = fmaxf(sa.z, 0.f); v[3] = fmaxf(sa.w, 0.f);
      v[4] = fmaxf(sb.x, 0.f); v[5] = fmaxf(sb.y, 0.f);
      v[6] = fmaxf(sb.z, 0.f); v[7] = fmaxf(sb.w, 0.f);
    }
    ushort4 h0, h1;
    h0.x = f2bf(v[0]); h0.y = f2bf(v[1]); h0.z = f2bf(v[2]); h0.w = f2bf(v[3]);
    h1.x = f2bf(v[4]); h1.y = f2bf(v[5]); h1.z = f2bf(v[6]); h1.w = f2bf(v[7]);
    const int slot = (f0 >> 3) ^ (row & 7);
    *(ushort4*)&xld[row * 64 + slot * 8] = h0;
    *(ushort4*)&xld[row * 64 + slot * 8 + 4] = h1;
  }
  __syncthreads();

#pragma unroll
  for (int lw = 0; lw < 3; ++lw) {
    const int l = wid * 3 + lw;
    f32x4 acc[4][2] = {};                    // [ot][kt]
#pragma unroll
    for (int ks = 0; ks < 2; ++ks) {
      bf16x8 bv[2];
#pragma unroll
      for (int kt = 0; kt < 2; ++kt) {
        const int kk = kt * 16 + r;
        bv[kt] = *(const bf16x8*)&xld[kk * 64 + (((ks * 4 + g) ^ (kk & 7)) << 3)];
      }
#pragma unroll
      for (int ot = 0; ot < 4; ++ot) {
        bf16x8 av = *(const bf16x8*)&wAf[(size_t)(l * 64 + ot * 16 + r) * 64 + ks * 32 + g * 8];
#pragma unroll
        for (int kt = 0; kt < 2; ++kt)
          acc[ot][kt] = __builtin_amdgcn_mfma_f32_16x16x32_bf16(av, bv[kt], acc[ot][kt], 0, 0, 0);
      }
    }
#pragma unroll
    for (int ot = 0; ot < 4; ++ot)
#pragma unroll
      for (int kt = 0; kt < 2; ++kt)
#pragma unroll
        for (int r2 = 0; r2 < 4; ++r2) {
          int o = ot * 16 + g * 4 + r2, k = kt * 16 + r;
          Z[l * 2304 + o * 36 + k] = (u16)fp8one(acc[ot][kt][r2] * YSCALE);
        }
  }
  __syncthreads();
  u8* yb = yT + (size_t)s * 393216;
#pragma unroll
  for (int it = 0; it < 8; ++it) {
    int idx = it * 256 + tid;                // 64 o x 32 k
    int o = idx >> 5, k = idx & 31;
    u32 b[12];
#pragma unroll
    for (int l = 0; l < 12; ++l) b[l] = (u32)(Z[l * 2304 + o * 36 + k] & 0xffu);
    u32* dst = (u32*)&yb[(size_t)o * 6144 + (size_t)(k0 + k) * 12];
    dst[0] = b[0] | (b[1] << 8) | (b[2] << 16) | (b[3] << 24);
    dst[1] = b[4] | (b[5] << 8) | (b[6] << 16) | (b[7] << 24);
    dst[2] = b[8] | (b[9] << 8) | (b[10] << 16) | (b[11] << 24);
  }
}

// ---------- stage B (fp8): counted-vmcnt 3-buffer pipeline ----------
// grid 512 (8 xcd x 2 s x 8 mt x 4 kq), 512 thr, 64x64 tile, BK=64, 24 steps.
// LDS rows 64 B; 16B-slot XOR X(row)=(row^(row>>2))&3, applied src-side + read-side.
__global__ __launch_bounds__(512, 2) void k_stageB(const u8* __restrict__ connQ,
                                                   const u8* __restrict__ yT,
                                                   float* __restrict__ pOut) {
  const int b = blockIdx.x;
  const int s = (b & 7) * 2 + ((b >> 3) & 1);
  const int mt = (b >> 4) & 7, kq = b >> 7;
  const int row0 = mt * 64, k0 = kq * 1536;
  const u8* Ab = connQ + (size_t)(s * 512 + row0) * 6144 + k0;
  const u8* Bb = yT + (size_t)(s * 64) * 6144 + k0;
  __shared__ __align__(16) u8 lds[3 * 2 * 4096];   // 24 KB: [buf][A|B][64*64]
  const int tid = threadIdx.x, lane = tid & 63, wid = tid >> 6;
  const int r = lane & 15, g = lane >> 4;
  const int wr = wid & 3, wc = wid >> 2;
  const int isA = wid < 4;
  const int wseg = (isA ? wid : wid - 4) * 16;     // 16-row staging segment
  const u8* sbase = isA ? Ab : Bb;
  const int lrow = lane >> 2, lslot = lane & 3;    // 16 rows x 4 slots of 16B
  const int side = isA ? 0 : 1;
  f32x4 acc[2] = {};

#define STAGE(T, NB)                                                            \
  {                                                                             \
    const int row = wseg + lrow;                                                \
    const int slot = lslot ^ ((row ^ (row >> 2)) & 3);                          \
    gload16(sbase + (size_t)row * 6144 + (size_t)(T) * 64 + slot * 16,          \
            &lds[((NB) * 2 + side) * 4096 + wseg * 64]);                        \
  }

  STAGE(0, 0);
  STAGE(1, 1);
  int nb = 0;
  for (int t = 0; t < 24; ++t) {
    if (t < 23) { asm volatile("s_waitcnt vmcnt(1)" ::: "memory"); }
    else        { asm volatile("s_waitcnt vmcnt(0)" ::: "memory"); }
    __builtin_amdgcn_s_barrier();
    if (t + 2 < 24) {
      int nb2 = nb + 2; if (nb2 >= 3) nb2 -= 3;
      STAGE(t + 2, nb2);
    }
    {
      const u8* bufA = &lds[(nb * 2 + 0) * 4096];
      const u8* bufB = &lds[(nb * 2 + 1) * 4096];
      const int arow = wr * 16 + r;
      const int ax = (arow ^ (arow >> 2)) & 3;
#pragma unroll
      for (int ks = 0; ks < 2; ++ks) {
        i64t av = *(const i64t*)&bufA[arow * 64 + (((ks * 2 + (g >> 1)) ^ ax) << 4) + ((g & 1) << 3)];
#pragma unroll
        for (int c = 0; c < 2; ++c) {
          const int col = wc * 32 + c * 16 + r;
          const int bx = (col ^ (col >> 2)) & 3;
          i64t bv = *(const i64t*)&bufB[col * 64 + (((ks * 2 + (g >> 1)) ^ bx) << 4) + ((g & 1) << 3)];
          acc[c] = __builtin_amdgcn_mfma_f32_16x16x32_fp8_fp8(av, bv, acc[c], 0, 0, 0);
        }
      }
    }
    if (++nb >= 3) nb -= 3;
  }
#undef STAGE
  float* po = pOut + (size_t)kq * 524288 + ((size_t)(s * 512) + row0) * 64;
#pragma unroll
  for (int c = 0; c < 2; ++c)
#pragma unroll
    for (int r2 = 0; r2 < 4; ++r2) {
      int m = wr * 16 + g * 4 + r2;
      int o = wc * 32 + c * 16 + r;
      po[m * 64 + o] = acc[c][r2];
    }
}

// ---------- final conv epilogue: d_out = relu(sum_q p[q]*YINV + bW + node) f32 ----------
__global__ __launch_bounds__(256) void k_finalLast(const float* __restrict__ pOut,
                                                   const float* __restrict__ bW,
                                                   const float* __restrict__ node,
                                                   float* __restrict__ outF) {
  size_t e = ((size_t)blockIdx.x * 256 + threadIdx.x) * 4;   // < 524288
  float4 sv = {0, 0, 0, 0};
#pragma unroll
  for (int q = 0; q < 4; ++q) {
    float4 a = *(const float4*)&pOut[(size_t)q * 524288 + e];
    sv.x += a.x; sv.y += a.y; sv.z += a.z; sv.w += a.w;
  }
  float4 bw = *(const float4*)&bW[e];
  float4 nd = *(const float4*)&node[e];
  sv.x = fmaxf(sv.x * YINV + bw.x + nd.x, 0.f);
  sv.y = fmaxf(sv.y * YINV + bw.y + nd.y, 0.f);
  sv.z = fmaxf(sv.z * YINV + bw.z + nd.z, 0.f);
  sv.w = fmaxf(sv.w * YINV + bw.w + nd.w, 0.f);
  *(float4*)&outF[e] = sv;
}

// ---------- fallback (f32, correct, slow) if ws too small ----------
__global__ __launch_bounds__(256) void k_fb_conv(const float* __restrict__ x,
                                                 const float* __restrict__ conn,
                                                 const float* __restrict__ bond,
                                                 const float* __restrict__ filt,
                                                 const float* __restrict__ node,
                                                 float* __restrict__ out, int addNode) {
  const int s = blockIdx.y, a = blockIdx.x;
  const int t = threadIdx.x;
  const int f = t & 63, lg = t >> 6;
  __shared__ float ncv[12 * 64];
  __shared__ float red[4][64];
  const float* cb = conn + ((size_t)(s * 512 + a)) * 6144;
  const float* xb = x + (size_t)s * 32768;
  float a0 = 0.f, a1 = 0.f, a2 = 0.f;
  for (int k = 0; k < 512; ++k) {
    float xv = xb[k * 64 + f];
    const float* cr = cb + k * 12 + lg * 3;
    a0 += cr[0] * xv; a1 += cr[1] * xv; a2 += cr[2] * xv;
  }
  ncv[(lg * 3 + 0) * 64 + f] = a0;
  ncv[(lg * 3 + 1) * 64 + f] = a1;
  ncv[(lg * 3 + 2) * 64 + f] = a2;
  __syncthreads();
  float p = 0.f;
  for (int l = lg * 3; l < lg * 3 + 3; ++l) {
    const float* wr = filt + ((size_t)(f * 12 + l)) * 66;
    float q = 0.f;
    for (int f2 = 0; f2 < 64; ++f2) q += ncv[l * 64 + f2] * wr[f2];
    q += bond[((size_t)(s * 512 + a) * 12 + l) * 2 + 0] * wr[64];
    q += bond[((size_t)(s * 512 + a) * 12 + l) * 2 + 1] * wr[65];
    p += q;
  }
  red[lg][f] = p;
  __syncthreads();
  if (t < 64) {
    float v = red[0][t] + red[1][t] + red[2][t] + red[3][t];
    if (addNode) v += node[((size_t)(s * 512 + a)) * 64 + t];
    out[((size_t)(s * 512 + a)) * 64 + t] = fmaxf(v, 0.f);
  }
}

extern "C" void kernel_launch(void* const* d_in, const int* in_sizes, int n_in,
                              void* d_out, int out_size, void* d_ws, size_t ws_size,
                              hipStream_t stream) {
  (void)in_sizes; (void)n_in; (void)out_size;
  const float* node    = (const float*)d_in[0];
  const float* conn    = (const float*)d_in[1];
  const float* bond    = (const float*)d_in[2];
  const float* filters = (const float*)d_in[3];
  float* outF = (float*)d_out;

  const size_t OFF_CONNQ = 0;           // 16*512*6144   = 50,331,648
  const size_t OFF_YT    = 50331648;    // 16*64*6144    =  6,291,456
  const size_t OFF_WA    = 56623104;    // 3*768*64*2    =    294,912
  const size_t OFF_BW    = 56918016;    // 3*16*512*64*4 =  6,291,456
  const size_t OFF_POUT  = 63209472;    // 4*16*512*64*4 =  8,388,608
  const size_t WS_NEED   = 71598080;

  if (ws_size >= WS_NEED) {
    unsigned char* ws = (unsigned char*)d_ws;
    u8*  connQ = (u8*)(ws + OFF_CONNQ);
    u8*  yTb   = (u8*)(ws + OFF_YT);
    u16* wA    = (u16*)(ws + OFF_WA);
    float* bW  = (float*)(ws + OFF_BW);
    float* pO  = (float*)(ws + OFF_POUT);

    k_prep<<<dim3(3136), dim3(256), 0, stream>>>(conn, filters, bond, connQ, wA, bW);
    k_yT<<<dim3(16, 16), dim3(256), 0, stream>>>(node, pO, bW, wA, yTb, 0, 0);
    for (int j = 0; j < 6; ++j) {
      k_stageB<<<dim3(512), dim3(512), 0, stream>>>(connQ, yTb, pO);
      if (j < 5) {
        k_yT<<<dim3(16, 16), dim3(256), 0, stream>>>(node, pO,
                                                     bW + (size_t)(j >> 1) * 524288,
                                                     wA + (size_t)((j + 1) >> 1) * 49152,
                                                     yTb, 1, j & 1);
      } else {
        k_finalLast<<<dim3(512), dim3(256), 0, stream>>>(pO, bW + (size_t)2 * 524288,
                                                         node, outF);
      }
    }
  } else {
    float* buf = (float*)d_ws;
    const float* xc = node;
    for (int j = 0; j < 6; ++j) {
      int i = j >> 1;
      float* dst = (j & 1) ? outF : buf;
      k_fb_conv<<<dim3(512, 16), dim3(256), 0, stream>>>(xc, conn, bond,
                                                         filters + (size_t)i * 50688,
                                                         node, dst, j & 1);
      xc = dst;
    }
  }
}